// Round 3
// baseline (383.472 us; speedup 1.0000x reference)
//
#include <hip/hip_runtime.h>
#include <cstdint>
#include <cstddef>

#define Bn 64
#define Hn 56
#define Wn 56
#define Cn 256
#define COn 64
#define RWn 64                              // route width = 256/4
#define XSZ ((size_t)Bn * Hn * Wn * RWn)    // 12,845,056 floats
#define NSd 14                              // row splits (divisor of 56)
#define RPSd (Hn / NSd)

__device__ __forceinline__ void f4add(float4& a, const float4& v) {
    a.x += v.x; a.y += v.y; a.z += v.z; a.w += v.w;
}
__device__ __forceinline__ float4 f4sub(const float4& a, const float4& b) {
    return make_float4(a.x - b.x, a.y - b.y, a.z - b.z, a.w - b.w);
}
__device__ __forceinline__ void f4fma(float4& a, float s, const float4& v) {
    a.x += s * v.x; a.y += s * v.y; a.z += s * v.z; a.w += s * v.w;
}

// ---------------------------------------------------------------------------
// Fused kernel: per-(batch, row-split) partial bin sums + (last block per
// batch) logits/argmax.
//
// S[b,kh,kw,ci] = sum over (ho,wo) of in[b, 2ho+kh, 2wo+kw, ci].
// Row h feeds kh=0 iff (h even, h<=52), kh=1 iff (h odd, h<=53),
// kh=2 iff (h even, 2<=h<=54); h==55 unused; same for columns.
// Within a wave, w = wb + wave has FIXED parity -> one running row-sum R
// plus two edge pixels folds into the 9 bins with <=6 float4 FMAs per row
// (wave-uniform branches).
//
// After writing its spart slot, each block does an acq_rel agent-scope
// arrival add; the LAST block for batch b reduces the NS slots, contracts
// with conv_w, computes logits + first-occurrence argmax -> routes[b].
// No spinning -> deadlock-free regardless of co-residency.
// ---------------------------------------------------------------------------
__global__ __launch_bounds__(256) void kA_fused(
        const float* __restrict__ in, float* __restrict__ spart,
        int* __restrict__ arrival, int* __restrict__ routes,
        const float* __restrict__ convw, const float* __restrict__ convb,
        const float* __restrict__ fcw,   const float* __restrict__ fcb,
        float* __restrict__ out_logits) {
    const int blk   = blockIdx.x;
    const int b     = blk / NSd;
    const int split = blk - b * NSd;
    const int tid   = threadIdx.x;
    const int lane  = tid & 63;
    const int wave  = tid >> 6;

    __shared__ union SM {
        float4 lds4[4][9][64];                       // 36 KB, phase-1 reduce
        struct { float sS[9 * 256]; float pP[4][64];
                 float pld[64]; float lgt[4]; } kb;  // phase-2 (last block)
    } sm;
    __shared__ int s_old;

    const float* base = in + (size_t)b * (Hn * Wn * Cn) + (size_t)lane * 4
                           + (size_t)wave * Cn;

    float4 acc[9];
#pragma unroll
    for (int k = 0; k < 9; ++k) acc[k] = make_float4(0.f, 0.f, 0.f, 0.f);

    const int h0 = split * RPSd;
    for (int h = h0; h < h0 + RPSd; ++h) {
        const bool  he  = (h & 1) == 0;
        const float rh0 = (he  && h <= 52)           ? 1.f : 0.f;
        const float rh1 = (!he && h <= 53)           ? 1.f : 0.f;
        const float rh2 = (he  && h >= 2 && h <= 54) ? 1.f : 0.f;
        if (rh0 == 0.f && rh1 == 0.f && rh2 == 0.f) continue;   // h == 55

        const float* rowp = base + (size_t)h * (Wn * Cn);
        float4 R  = make_float4(0.f, 0.f, 0.f, 0.f);
        float4 e0 = R, e1 = R;   // edge pixels: w==0 (wave0), w==54 (wave2)
#pragma unroll
        for (int wb = 0; wb < Wn; wb += 4) {
            if (wb == 52 && wave == 3) continue;    // w==55 never used (uniform)
            const float4 v = *(const float4*)(rowp + (size_t)wb * Cn);
            if (wb == 0)  e0 = v;
            if (wb == 52) e1 = v;
            f4add(R, v);
        }

        const float rhE[3] = { rh0, rh1, rh2 };
        if ((wave & 1) == 0) {          // wave-uniform: no divergence
            float4 cA, cB;              // contributions to kw=0, kw=2
            if (wave == 0) { cA = R;            cB = f4sub(R, e0); }
            else           { cA = f4sub(R, e1); cB = R;            }
#pragma unroll
            for (int kh = 0; kh < 3; ++kh) {
                f4fma(acc[kh * 3 + 0], rhE[kh], cA);
                f4fma(acc[kh * 3 + 2], rhE[kh], cB);
            }
        } else {                        // kw=1 from odd waves
#pragma unroll
            for (int kh = 0; kh < 3; ++kh)
                f4fma(acc[kh * 3 + 1], rhE[kh], R);
        }
    }

    // reduce the 4 waves' partials via LDS, write this block's spart slot
#pragma unroll
    for (int k = 0; k < 9; ++k) sm.lds4[wave][k][lane] = acc[k];
    __syncthreads();

    {
        const float* ldsf = (const float*)sm.lds4;
        float* op = spart + (((size_t)b * NSd + split) * 9) * 256;
#pragma unroll
        for (int k = 0; k < 9; ++k) {
            const float s = ldsf[(0 * 9 + k) * 256 + tid] + ldsf[(1 * 9 + k) * 256 + tid]
                          + ldsf[(2 * 9 + k) * 256 + tid] + ldsf[(3 * 9 + k) * 256 + tid];
            op[k * 256 + tid] = s;             // coalesced
        }
    }
    __syncthreads();   // everyone done with lds4 before potential reuse

    // arrival: last block for batch b does the kB work
    if (tid == 0) {
        s_old = __hip_atomic_fetch_add(&arrival[b], 1,
                                       __ATOMIC_ACQ_REL, __HIP_MEMORY_SCOPE_AGENT);
    }
    __syncthreads();
    if (s_old != NSd - 1) return;

    const int t = tid;
    // reduce split partials (coalesced)
#pragma unroll
    for (int k = 0; k < 9; ++k) {
        float a = 0.f;
#pragma unroll
        for (int s = 0; s < NSd; ++s)
            a += spart[(((size_t)b * NSd + s) * 9 + k) * 256 + t];
        sm.kb.sS[k * 256 + t] = a;
    }
    __syncthreads();

    // contraction: part = t>>6 handles 64 input channels, co = t&63
    {
        const int co = t & 63, part = t >> 6;
        float a = 0.f;
#pragma unroll
        for (int k = 0; k < 9; ++k) {
            const int cb = part * 64;
#pragma unroll 8
            for (int ci = 0; ci < 64; ++ci)
                a += sm.kb.sS[k * 256 + cb + ci] * convw[(size_t)(k * 256 + cb + ci) * 64 + co];
        }
        sm.kb.pP[part][co] = a;
    }
    __syncthreads();

    if (t < 64)
        sm.kb.pld[t] = (sm.kb.pP[0][t] + sm.kb.pP[1][t] + sm.kb.pP[2][t] + sm.kb.pP[3][t])
                       * (1.f / 729.f) + convb[t];
    __syncthreads();

    if (t < 4) {
        float a = fcb[t];
#pragma unroll
        for (int co = 0; co < 64; ++co) a += sm.kb.pld[co] * fcw[co * 4 + t];
        sm.kb.lgt[t] = a;
        out_logits[b * 4 + t] = a;
    }
    __syncthreads();

    if (t == 0) {
        int bi = 0; float best = sm.kb.lgt[0];
#pragma unroll
        for (int r = 1; r < 4; ++r) if (sm.kb.lgt[r] > best) { best = sm.kb.lgt[r]; bi = r; }
        routes[b] = bi;   // visible to next dispatch via kernel-boundary ordering
    }
}

// ---------------------------------------------------------------------------
// Kernel C: routed channel-group gather. 4 float4 per thread.
// total float4 = 64*56*56*16 = 3,211,264 = 3136 blocks * 256 thr * 4.
// ---------------------------------------------------------------------------
__global__ __launch_bounds__(256) void kC_gather(
        const float* __restrict__ in, const int* __restrict__ routes,
        float* __restrict__ out) {
#pragma unroll
    for (int k = 0; k < 4; ++k) {
        const size_t idx = (size_t)blockIdx.x * 1024 + k * 256 + threadIdx.x;
        const size_t pix = idx >> 4;
        const int   f4i  = (int)(idx & 15);
        const int   b    = (int)(pix / (Hn * Wn));
        const int   r    = routes[b];
        const float4 v = *(const float4*)(in + pix * (size_t)Cn
                                          + (size_t)r * RWn + (size_t)f4i * 4);
        ((float4*)out)[idx] = v;
    }
}

extern "C" void kernel_launch(void* const* d_in, const int* in_sizes, int n_in,
                              void* d_out, int out_size, void* d_ws, size_t ws_size,
                              hipStream_t stream) {
    const float* in    = (const float*)d_in[0];
    const float* convw = (const float*)d_in[1];
    const float* convb = (const float*)d_in[2];
    const float* fcw   = (const float*)d_in[3];
    const float* fcb   = (const float*)d_in[4];
    float* out = (float*)d_out;

    const size_t spartBytes = (size_t)Bn * NSd * 9 * 256 * sizeof(float); // 12.9 MB
    float* spart   = (float*)d_ws;
    int*   arrival = (int*)((char*)d_ws + spartBytes);
    int*   routes  = arrival + Bn;

    // zero the arrival counters (graph-capturable memset node; ws is poisoned)
    hipMemsetAsync(arrival, 0, Bn * sizeof(int), stream);

    kA_fused <<<Bn * NSd, 256, 0, stream>>>(in, spart, arrival, routes,
                                            convw, convb, fcw, fcb, out + XSZ);
    kC_gather<<<3136,     256, 0, stream>>>(in, routes, out);
}